// Round 4
// baseline (386.185 us; speedup 1.0000x reference)
//
#include <hip/hip_runtime.h>
#include <cstdint>

#define NH 16
#define DH 64
#define FF 4096
#define PP 512
#define BB 2048

typedef __bf16 bf16x8 __attribute__((ext_vector_type(8)));
typedef float f32x4 __attribute__((ext_vector_type(4)));
typedef float fl4 __attribute__((ext_vector_type(4)));
typedef unsigned short us4 __attribute__((ext_vector_type(4)));
typedef unsigned int u32x2 __attribute__((ext_vector_type(2)));

__device__ __forceinline__ unsigned short f2bf(float f) {
  unsigned u = __float_as_uint(f);
  u += 0x7FFFu + ((u >> 16) & 1u);
  return (unsigned short)(u >> 16);
}

// pack two f32 -> two bf16 (round-half-up: +0x8000, take high16s via v_perm)
__device__ __forceinline__ unsigned int pkbf(float lo, float hi) {
  unsigned a = __float_as_uint(lo) + 0x8000u;
  unsigned b = __float_as_uint(hi) + 0x8000u;
  return __builtin_amdgcn_perm(b, a, 0x07060302u);
}

// async global->LDS, 16B/lane. LDS dest = wave-uniform base + lane*16;
// global source is per-lane arbitrary (exploited for the XOR swizzle).
__device__ __forceinline__ void gload_lds16(const void* g, void* l) {
  __builtin_amdgcn_global_load_lds(
      (const __attribute__((address_space(1))) void*)g,
      (__attribute__((address_space(3))) void*)(unsigned int)(unsigned long long)l,
      16, 0, 0);
}

// convert features + prototypes fp32 -> bf16 (x is consumed fp32 directly)
__global__ void cvt_fp(const float* __restrict__ f, const float* __restrict__ p,
                       unsigned short* __restrict__ fb,
                       unsigned short* __restrict__ pb) {
  const int nf = FF * 1024 / 4, np = PP * 1024 / 4;
  int i = blockIdx.x * blockDim.x + threadIdx.x;
  const fl4* src;
  us4* dst;
  if (i < nf) {
    src = (const fl4*)f + i;
    dst = (us4*)fb + i;
  } else if (i < nf + np) {
    src = (const fl4*)p + (i - nf);
    dst = (us4*)pb + (i - nf);
  } else {
    return;
  }
  fl4 v = *src;
  us4 o;
  o.x = f2bf(v.x); o.y = f2bf(v.y); o.z = f2bf(v.z); o.w = f2bf(v.w);
  *dst = o;
}

// ---------------------------------------------------------------------------
// Phase 1: per-head [P x F, K=64] GEMM on prototypes.
//   Q1 = th*Pw + al*Pp - al,  Q2 = be*Pw   (layout [h][p][f], bf16)
//   pws[h][p] += be * sum_f Pw
// ---------------------------------------------------------------------------
__global__ __launch_bounds__(256, 2) void gemm_proto(
    const unsigned short* __restrict__ Abf, const unsigned short* __restrict__ Fbf,
    unsigned short* __restrict__ O1, unsigned short* __restrict__ O2,
    float* __restrict__ pws,
    const float* __restrict__ theta, const float* __restrict__ alpha,
    const float* __restrict__ beta) {
  const int h = blockIdx.z;
  const int n0 = blockIdx.x * 128;   // f tile
  const int lm0 = blockIdx.y * 128;  // p tile
  const int t = threadIdx.x;

  __shared__ __align__(16) char As[128 * 128];
  __shared__ __align__(16) char Bs[128 * 128];

  {
    const char* ab = (const char*)(Abf + (size_t)lm0 * 1024 + h * 64);
    const char* bb = (const char*)(Fbf + (size_t)n0 * 1024 + h * 64);
#pragma unroll
    for (int r = 0; r < 4; ++r) {
      int o = r * 4096 + t * 16;
      int row = o >> 7, col = o & 127;
      gload_lds16(ab + (size_t)row * 2048 + col, As + o);
      gload_lds16(bb + (size_t)row * 2048 + col, Bs + o);
    }
  }
  __syncthreads();

  const int wave = t >> 6, lane = t & 63;
  const int wm = wave & 1, wn = wave >> 1;
  const int quad = lane >> 4, lr = lane & 15;

  f32x4 acc[4][4];
#pragma unroll
  for (int i = 0; i < 4; ++i)
#pragma unroll
    for (int j = 0; j < 4; ++j) acc[i][j] = (f32x4){0.f, 0.f, 0.f, 0.f};

#pragma unroll
  for (int s = 0; s < 2; ++s) {
    bf16x8 av[4], bv[4];
#pragma unroll
    for (int fm = 0; fm < 4; ++fm) {
      int row = wm * 64 + fm * 16 + lr;
      av[fm] = *(const bf16x8*)(As + row * 128 + s * 64 + quad * 16);
    }
#pragma unroll
    for (int fn = 0; fn < 4; ++fn) {
      int row = wn * 64 + fn * 16 + lr;
      bv[fn] = *(const bf16x8*)(Bs + row * 128 + s * 64 + quad * 16);
    }
#pragma unroll
    for (int fm = 0; fm < 4; ++fm)
#pragma unroll
      for (int fn = 0; fn < 4; ++fn)
        acc[fm][fn] = __builtin_amdgcn_mfma_f32_16x16x32_bf16(av[fm], bv[fn],
                                                              acc[fm][fn], 0, 0, 0);
  }

  const float th = theta[h], al = alpha[h], be = beta[h];

#pragma unroll
  for (int fm = 0; fm < 4; ++fm) {
    int prow = lm0 + wm * 64 + fm * 16 + quad * 4;
    float rs0 = 0.f, rs1 = 0.f, rs2 = 0.f, rs3 = 0.f;
#pragma unroll
    for (int fn = 0; fn < 4; ++fn) {
      int f = n0 + wn * 64 + fn * 16 + lr;
#pragma unroll
      for (int i = 0; i < 4; ++i) {
        float pf = acc[fm][fn][i];
        float pp = fmaxf(pf, 0.f);
        float pw = pf * pp;
        size_t idx = ((size_t)(h * PP + prow + i)) * FF + f;
        O1[idx] = f2bf(th * pw + al * pp - al);
        O2[idx] = f2bf(be * pw);
        if (i == 0) rs0 += pw;
        else if (i == 1) rs1 += pw;
        else if (i == 2) rs2 += pw;
        else rs3 += pw;
      }
    }
    float rs[4] = {rs0, rs1, rs2, rs3};
#pragma unroll
    for (int i = 0; i < 4; ++i) {
      float s = rs[i];
      s += __shfl_xor(s, 1);
      s += __shfl_xor(s, 2);
      s += __shfl_xor(s, 4);
      s += __shfl_xor(s, 8);
      if (lr == 0) atomicAdd(&pws[h * PP + prow + i], be * s);
    }
  }
}

// ---------------------------------------------------------------------------
// Fused main, round-9: software-pipelined single-barrier loop.
//   Round-3 showed FETCH collapsed (Q is L2-hit) but dur unchanged ->
//   bottleneck is the serial B->C->bar->D->bar chain, not memory. Now
//   body(it) = { Q(it) loads; stage sF(it+2); B(it+1)+C(it+1); D(it) } with
//   ONE fused vmcnt(0)+lgkmcnt(0)+s_barrier at body end. B/C of the next
//   iteration are independent of D(it), so the scheduler interleaves them
//   into D's Q-latency window; steady-state critical path is D-to-D.
//   Buffers: sF ping-pong (tile k in buf[k&1]); sXw/sXp ping-pong
//   (D(it) reads buf[it&1], C(it+1) writes buf[(it+1)&1]).
//   Last body computes one garbage B/C tile from the 64-row f_bf pad
//   (written to LDS, never read).
//   Q1/Q2 in registers (1x4 wave decomposition); XCD-aware 1-D decode (T1)
//   keeps all 16 Q-sharing blocks on one XCD -> Q loads are L2 hits.
//   Fused waitcnt+s_barrier single asm blocks (round-7 race fix).
// LDS = 8 (sF x2) + 16 (sXw x2) + 16 (sXp x2) = 40 KB; 2 blocks/CU.
// ---------------------------------------------------------------------------
__global__ __launch_bounds__(256, 2) void fused_main(
    const float* __restrict__ x, const unsigned short* __restrict__ f_bf,
    const unsigned short* __restrict__ Q1, const unsigned short* __restrict__ Q2,
    const float* __restrict__ pws, float* __restrict__ out) {
  // XCD-aware decode: l -> (p-tile, head, b-tile) with Q-sharers co-located.
  const int l = blockIdx.x;        // 0..511
  const int i = l >> 3;            // 0..63 within XCD
  const int g = (l & 7) * 4 + (i & 3);  // group = (p-tile, head), 0..31
  const int h = g >> 1;
  const int n0 = (g & 1) * 256;    // p tile
  const int m0 = (i >> 2) * 128;   // b tile
  const int t = threadIdx.x;
  const int wave = t >> 6, lane = t & 63;
  const int quad = lane >> 4, lr = lane & 15;
  const int key8 = lr & 7;         // swizzle key for 128B-row buffer (sF)
  const int key2 = (lr >> 1) & 3;  // swizzle key for 64B-row buffers (sX*)

  __shared__ __align__(16) char sF[2 * 4096];
  __shared__ __align__(16) char sXw[2 * 8192];
  __shared__ __align__(16) char sXp[2 * 8192];

  // Xh B-operand fragments, loaded fp32 and packed in-register.
  bf16x8 xh[2][2];
#pragma unroll
  for (int bn = 0; bn < 2; ++bn)
#pragma unroll
    for (int s = 0; s < 2; ++s) {
      int b = m0 + wave * 32 + bn * 16 + lr;
      const float* xr = x + (size_t)b * 1024 + h * 64 + s * 32 + quad * 8;
      fl4 v0 = *(const fl4*)xr;
      fl4 v1 = *(const fl4*)(xr + 4);
      union { unsigned u[4]; bf16x8 v; } cv;
      cv.u[0] = pkbf(v0.x, v0.y);
      cv.u[1] = pkbf(v0.z, v0.w);
      cv.u[2] = pkbf(v1.x, v1.y);
      cv.u[3] = pkbf(v1.z, v1.w);
      xh[bn][s] = cv.v;
    }

  // ---- hoisted (loop-invariant) LDS byte offsets ----
  int af_off[2][2];  // B reads: sF row fm*16+lr, global chunk s*4+quad
#pragma unroll
  for (int fm = 0; fm < 2; ++fm)
#pragma unroll
    for (int s = 0; s < 2; ++s)
      af_off[fm][s] = (fm * 16 + lr) * 128 + (((s * 4 + quad) ^ key8) * 16);

  int cw_off[2][2];  // C writes: row wave*32+bn*16+lr, chunk fm*2+(quad>>1)
#pragma unroll
  for (int fm = 0; fm < 2; ++fm)
#pragma unroll
    for (int bn = 0; bn < 2; ++bn)
      cw_off[fm][bn] = (wave * 32 + bn * 16 + lr) * 64 +
                       (((fm * 2 + (quad >> 1)) ^ key2) * 16) + (quad & 1) * 8;

  int aw_off[8];  // D A reads: row fm*16+lr (all 128 b rows), chunk quad
#pragma unroll
  for (int fm = 0; fm < 8; ++fm)
    aw_off[fm] = (fm * 16 + lr) * 64 + ((quad ^ key2) * 16);

  // sF staging source (swizzle applied on the GLOBAL side)
  const char* srcF;
  {
    int row = t >> 3, c = t & 7, cs = c ^ (row & 7);
    srcF = (const char*)f_bf + h * 128 + (size_t)row * 2048 + cs * 16;
  }

  // per-wave Q row pointers: wave owns p = n0 + wave*64 .. +63
  const unsigned short* qrow1 =
      Q1 + (size_t)(h * PP + n0 + wave * 64 + lr) * FF + quad * 8;
  const unsigned short* qrow2 =
      Q2 + (size_t)(h * PP + n0 + wave * 64 + lr) * FF + quad * 8;

  f32x4 acc[8][4];
#pragma unroll
  for (int i2 = 0; i2 < 8; ++i2)
#pragma unroll
    for (int j = 0; j < 4; ++j) acc[i2][j] = (f32x4){0.f, 0.f, 0.f, 0.f};

  // B(k)+C(k): Xf from sF buf sfb, transform, pack into sXw/sXp buf xb.
  auto runBC = [&](int sfb, int xb) {
    f32x4 xf[2][2];
#pragma unroll
    for (int fm = 0; fm < 2; ++fm)
#pragma unroll
      for (int bn = 0; bn < 2; ++bn) xf[fm][bn] = (f32x4){0.f, 0.f, 0.f, 0.f};
#pragma unroll
    for (int s = 0; s < 2; ++s)
#pragma unroll
      for (int fm = 0; fm < 2; ++fm) {
        bf16x8 af = *(const bf16x8*)(sF + sfb + af_off[fm][s]);
#pragma unroll
        for (int bn = 0; bn < 2; ++bn)
          xf[fm][bn] = __builtin_amdgcn_mfma_f32_16x16x32_bf16(af, xh[bn][s],
                                                               xf[fm][bn], 0, 0, 0);
      }
#pragma unroll
    for (int fm = 0; fm < 2; ++fm)
#pragma unroll
      for (int bn = 0; bn < 2; ++bn) {
        float v0 = xf[fm][bn][0], v1 = xf[fm][bn][1];
        float v2 = xf[fm][bn][2], v3 = xf[fm][bn][3];
        float p0 = fmaxf(v0, 0.f), p1 = fmaxf(v1, 0.f);
        float p2 = fmaxf(v2, 0.f), p3 = fmaxf(v3, 0.f);
        u32x2 w, p;
        w.x = pkbf(v0 * p0, v1 * p1);
        w.y = pkbf(v2 * p2, v3 * p3);
        p.x = pkbf(p0, p1);
        p.y = pkbf(p2, p3);
        *(u32x2*)(sXw + xb + cw_off[fm][bn]) = w;
        *(u32x2*)(sXp + xb + cw_off[fm][bn]) = p;
      }
  };

  // ---- prologue ----
  // tile0 -> sF buf0
  gload_lds16(srcF, sF + t * 16);
  srcF += 32 * 2048;
  asm volatile("s_waitcnt vmcnt(0)\n\ts_barrier" ::: "memory");
  __builtin_amdgcn_sched_barrier(0);
  // tile1 -> sF buf1 (in flight across the next barrier is NOT allowed:
  // body(0)'s B(1) reads it, so drain at the prologue-end barrier below)
  gload_lds16(srcF, sF + 4096 + t * 16);
  srcF += 32 * 2048;
  // B(0)+C(0) -> sXw/sXp buf0
  runBC(0, 0);
  asm volatile("s_waitcnt vmcnt(0) lgkmcnt(0)\n\ts_barrier" ::: "memory");
  __builtin_amdgcn_sched_barrier(0);

  for (int it = 0; it < FF / 32; ++it) {
    const int pA = it & 1;   // D reads sXw/sXp[pA]; stage writes sF[pA]
    const int pB = pA ^ 1;   // B reads sF[pB]; C writes sXw/sXp[pB]

    // Q fragment loads for D(it) (L2 hits thanks to XCD co-location; their
    // latency hides under B(it+1)/C(it+1) scheduled before D's consumption)
    bf16x8 q1v[4], q2v[4];
#pragma unroll
    for (int fn = 0; fn < 4; ++fn) {
      q1v[fn] = *(const bf16x8*)(qrow1 + fn * (16 * FF));
      q2v[fn] = *(const bf16x8*)(qrow2 + fn * (16 * FF));
    }
    qrow1 += 32;
    qrow2 += 32;

    // stage tile it+2 -> sF[pA] (completes well before the end barrier)
    gload_lds16(srcF, sF + pA * 4096 + t * 16);
    srcF += 32 * 2048;

    // B(it+1)+C(it+1): independent of D(it); fills D's Q-latency window.
    runBC(pB * 4096, pB * 8192);

    // D(it): acc += Xw.Q1^T + Xp.Q2^T  (A from LDS[pA], B from registers)
    __builtin_amdgcn_s_setprio(1);
#pragma unroll
    for (int hf = 0; hf < 2; ++hf) {
      bf16x8 aw[4], ap[4];
#pragma unroll
      for (int fm = 0; fm < 4; ++fm) {
        aw[fm] = *(const bf16x8*)(sXw + pA * 8192 + aw_off[hf * 4 + fm]);
        ap[fm] = *(const bf16x8*)(sXp + pA * 8192 + aw_off[hf * 4 + fm]);
      }
#pragma unroll
      for (int fn = 0; fn < 4; ++fn)
#pragma unroll
        for (int fm = 0; fm < 4; ++fm) {
          acc[hf * 4 + fm][fn] = __builtin_amdgcn_mfma_f32_16x16x32_bf16(
              aw[fm], q1v[fn], acc[hf * 4 + fm][fn], 0, 0, 0);
          acc[hf * 4 + fm][fn] = __builtin_amdgcn_mfma_f32_16x16x32_bf16(
              ap[fm], q2v[fn], acc[hf * 4 + fm][fn], 0, 0, 0);
        }
    }
    __builtin_amdgcn_s_setprio(0);

    // single per-body barrier: publishes C(it+1)'s sX writes for D(it+1),
    // drains the sF stage (read by B(it+2) next body), and closes D(it)'s
    // sX reads before C(it+2) overwrites that buffer.
    asm volatile("s_waitcnt vmcnt(0) lgkmcnt(0)\n\ts_barrier" ::: "memory");
    __builtin_amdgcn_sched_barrier(0);
  }

  // epilogue: subtract pws, store fp32
#pragma unroll
  for (int fn = 0; fn < 4; ++fn) {
    int p = n0 + wave * 64 + fn * 16 + lr;
    float sub = pws[h * PP + p];
#pragma unroll
    for (int fm = 0; fm < 8; ++fm) {
      int brow = m0 + fm * 16 + quad * 4;
#pragma unroll
      for (int i2 = 0; i2 < 4; ++i2) {
        out[(size_t)(brow + i2) * (NH * PP) + h * PP + p] = acc[fm][fn][i2] - sub;
      }
    }
  }
}

extern "C" void kernel_launch(void* const* d_in, const int* in_sizes, int n_in,
                              void* d_out, int out_size, void* d_ws, size_t ws_size,
                              hipStream_t stream) {
  const float* x = (const float*)d_in[0];
  const float* features = (const float*)d_in[1];
  const float* prototypes = (const float*)d_in[2];
  const float* theta = (const float*)d_in[3];
  const float* alpha = (const float*)d_in[4];
  const float* beta = (const float*)d_in[5];
  float* out = (float*)d_out;

  char* ws = (char*)d_ws;
  size_t off = 0;
  auto carve = [&](size_t bytes) -> char* {
    char* p = ws + off;
    off += (bytes + 255) & ~(size_t)255;
    return p;
  };
  // f_bf padded by 64 rows: fused_main's pipelined loop prefetches up to two
  // tiles past the end (data unused; keeps the main loop branch-free).
  unsigned short* f_bf = (unsigned short*)carve((size_t)(FF + 64) * 1024 * 2);
  unsigned short* p_bf = (unsigned short*)carve((size_t)PP * 1024 * 2);
  unsigned short* Q1 = (unsigned short*)carve((size_t)NH * PP * FF * 2);
  unsigned short* Q2 = (unsigned short*)carve((size_t)NH * PP * FF * 2);
  float* pws = (float*)carve((size_t)NH * PP * 4);

  const int ncvt = (FF + PP) * 1024 / 4;
  cvt_fp<<<(ncvt + 255) / 256, 256, 0, stream>>>(features, prototypes, f_bf, p_bf);
  hipMemsetAsync(pws, 0, (size_t)NH * PP * 4, stream);

  // Phase 1: prototypes -> Q1, Q2, pws
  gemm_proto<<<dim3(FF / 128, PP / 128, NH), 256, 0, stream>>>(
      p_bf, f_bf, Q1, Q2, pws, theta, alpha, beta);

  // Fused main GEMM (1-D grid, XCD-aware decode in-kernel)
  fused_main<<<dim3(512, 1, 1), 256, 0, stream>>>(
      x, f_bf, Q1, Q2, pws, out);
}

// Round 6
// 382.996 us; speedup vs baseline: 1.0083x; 1.0083x over previous
//
#include <hip/hip_runtime.h>
#include <cstdint>

#define NH 16
#define DH 64
#define FF 4096
#define PP 512
#define BB 2048

typedef __bf16 bf16x8 __attribute__((ext_vector_type(8)));
typedef float f32x4 __attribute__((ext_vector_type(4)));
typedef float fl4 __attribute__((ext_vector_type(4)));
typedef unsigned short us4 __attribute__((ext_vector_type(4)));
typedef unsigned int u32x2 __attribute__((ext_vector_type(2)));

__device__ __forceinline__ unsigned short f2bf(float f) {
  unsigned u = __float_as_uint(f);
  u += 0x7FFFu + ((u >> 16) & 1u);
  return (unsigned short)(u >> 16);
}

// pack two f32 -> two bf16 (round-half-up: +0x8000, take high16s via v_perm)
__device__ __forceinline__ unsigned int pkbf(float lo, float hi) {
  unsigned a = __float_as_uint(lo) + 0x8000u;
  unsigned b = __float_as_uint(hi) + 0x8000u;
  return __builtin_amdgcn_perm(b, a, 0x07060302u);
}

// async global->LDS, 16B/lane. LDS dest = wave-uniform base + lane*16;
// global source is per-lane arbitrary (exploited for the XOR swizzle).
__device__ __forceinline__ void gload_lds16(const void* g, void* l) {
  __builtin_amdgcn_global_load_lds(
      (const __attribute__((address_space(1))) void*)g,
      (__attribute__((address_space(3))) void*)(unsigned int)(unsigned long long)l,
      16, 0, 0);
}

// convert features + prototypes fp32 -> bf16 (x is consumed fp32 directly)
__global__ void cvt_fp(const float* __restrict__ f, const float* __restrict__ p,
                       unsigned short* __restrict__ fb,
                       unsigned short* __restrict__ pb) {
  const int nf = FF * 1024 / 4, np = PP * 1024 / 4;
  int i = blockIdx.x * blockDim.x + threadIdx.x;
  const fl4* src;
  us4* dst;
  if (i < nf) {
    src = (const fl4*)f + i;
    dst = (us4*)fb + i;
  } else if (i < nf + np) {
    src = (const fl4*)p + (i - nf);
    dst = (us4*)pb + (i - nf);
  } else {
    return;
  }
  fl4 v = *src;
  us4 o;
  o.x = f2bf(v.x); o.y = f2bf(v.y); o.z = f2bf(v.z); o.w = f2bf(v.w);
  *dst = o;
}

// ---------------------------------------------------------------------------
// Phase 1: per-head [P x F, K=64] GEMM on prototypes.
//   Q1 = th*Pw + al*Pp - al,  Q2 = be*Pw   (layout [h][p][f], bf16)
//   pws[h][p] += be * sum_f Pw
// ---------------------------------------------------------------------------
__global__ __launch_bounds__(256, 2) void gemm_proto(
    const unsigned short* __restrict__ Abf, const unsigned short* __restrict__ Fbf,
    unsigned short* __restrict__ O1, unsigned short* __restrict__ O2,
    float* __restrict__ pws,
    const float* __restrict__ theta, const float* __restrict__ alpha,
    const float* __restrict__ beta) {
  const int h = blockIdx.z;
  const int n0 = blockIdx.x * 128;   // f tile
  const int lm0 = blockIdx.y * 128;  // p tile
  const int t = threadIdx.x;

  __shared__ __align__(16) char As[128 * 128];
  __shared__ __align__(16) char Bs[128 * 128];

  {
    const char* ab = (const char*)(Abf + (size_t)lm0 * 1024 + h * 64);
    const char* bb = (const char*)(Fbf + (size_t)n0 * 1024 + h * 64);
#pragma unroll
    for (int r = 0; r < 4; ++r) {
      int o = r * 4096 + t * 16;
      int row = o >> 7, col = o & 127;
      gload_lds16(ab + (size_t)row * 2048 + col, As + o);
      gload_lds16(bb + (size_t)row * 2048 + col, Bs + o);
    }
  }
  __syncthreads();

  const int wave = t >> 6, lane = t & 63;
  const int wm = wave & 1, wn = wave >> 1;
  const int quad = lane >> 4, lr = lane & 15;

  f32x4 acc[4][4];
#pragma unroll
  for (int i = 0; i < 4; ++i)
#pragma unroll
    for (int j = 0; j < 4; ++j) acc[i][j] = (f32x4){0.f, 0.f, 0.f, 0.f};

#pragma unroll
  for (int s = 0; s < 2; ++s) {
    bf16x8 av[4], bv[4];
#pragma unroll
    for (int fm = 0; fm < 4; ++fm) {
      int row = wm * 64 + fm * 16 + lr;
      av[fm] = *(const bf16x8*)(As + row * 128 + s * 64 + quad * 16);
    }
#pragma unroll
    for (int fn = 0; fn < 4; ++fn) {
      int row = wn * 64 + fn * 16 + lr;
      bv[fn] = *(const bf16x8*)(Bs + row * 128 + s * 64 + quad * 16);
    }
#pragma unroll
    for (int fm = 0; fm < 4; ++fm)
#pragma unroll
      for (int fn = 0; fn < 4; ++fn)
        acc[fm][fn] = __builtin_amdgcn_mfma_f32_16x16x32_bf16(av[fm], bv[fn],
                                                              acc[fm][fn], 0, 0, 0);
  }

  const float th = theta[h], al = alpha[h], be = beta[h];

#pragma unroll
  for (int fm = 0; fm < 4; ++fm) {
    int prow = lm0 + wm * 64 + fm * 16 + quad * 4;
    float rs0 = 0.f, rs1 = 0.f, rs2 = 0.f, rs3 = 0.f;
#pragma unroll
    for (int fn = 0; fn < 4; ++fn) {
      int f = n0 + wn * 64 + fn * 16 + lr;
#pragma unroll
      for (int i = 0; i < 4; ++i) {
        float pf = acc[fm][fn][i];
        float pp = fmaxf(pf, 0.f);
        float pw = pf * pp;
        size_t idx = ((size_t)(h * PP + prow + i)) * FF + f;
        O1[idx] = f2bf(th * pw + al * pp - al);
        O2[idx] = f2bf(be * pw);
        if (i == 0) rs0 += pw;
        else if (i == 1) rs1 += pw;
        else if (i == 2) rs2 += pw;
        else rs3 += pw;
      }
    }
    float rs[4] = {rs0, rs1, rs2, rs3};
#pragma unroll
    for (int i = 0; i < 4; ++i) {
      float s = rs[i];
      s += __shfl_xor(s, 1);
      s += __shfl_xor(s, 2);
      s += __shfl_xor(s, 4);
      s += __shfl_xor(s, 8);
      if (lr == 0) atomicAdd(&pws[h * PP + prow + i], be * s);
    }
  }
}

// ---------------------------------------------------------------------------
// Fused main, round-11: hand-interleaved C/D stream (round-10 fixed).
//   Round-5 bug: DREAD(1) overwrote aw/ap BEFORE DMFMA(0,1) consumed them
//   (operand-lifetime error in the hand interleave). Fix: DREAD(1) moved
//   AFTER DMFMA(0,1) in the same fence region -- the scheduler still hoists
//   the ds_reads under those 16 MFMAs (WAR lets each read issue once its
//   register's last MFMA consumer has issued), so hf1 operands are ready
//   for DMFMA(1,0) without a second register set (which would blow the
//   unified VGPR budget: acc=128 + q=32 + aw/ap=32 + xf/xh=32 + ~108 arch).
//   Theory under test (round-4 post-mortem): MfmaUtil pinned at ~45%
//   because each wave issues ~220cy C VALU then ~310cy D MFMA in order;
//   interleaving {C group + 16 MFMA} x4 feeds the matrix pipe continuously.
//   Retains: Q in registers (1x4 decomposition, SGPR base + 32b voffset),
//   XCD-aware decode (T1, Q re-reads L2-hit), B/C one iteration ahead,
//   single fused vmcnt+lgkmcnt+s_barrier per body (round-7 race fix).
// LDS = 8 (sF x2) + 16 (sXw x2) + 16 (sXp x2) = 40 KB; 2 blocks/CU.
// ---------------------------------------------------------------------------
__global__ __launch_bounds__(256, 2) void fused_main(
    const float* __restrict__ x, const unsigned short* __restrict__ f_bf,
    const unsigned short* __restrict__ Q1, const unsigned short* __restrict__ Q2,
    const float* __restrict__ pws, float* __restrict__ out) {
  // XCD-aware decode: l -> (p-tile, head, b-tile) with Q-sharers co-located.
  const int l = blockIdx.x;        // 0..511
  const int i = l >> 3;            // 0..63 within XCD
  const int g = (l & 7) * 4 + (i & 3);  // group = (p-tile, head), 0..31
  const int h = g >> 1;
  const int n0 = (g & 1) * 256;    // p tile
  const int m0 = (i >> 2) * 128;   // b tile
  const int t = threadIdx.x;
  const int wave = t >> 6, lane = t & 63;
  const int quad = lane >> 4, lr = lane & 15;
  const int key8 = lr & 7;         // swizzle key for 128B-row buffer (sF)
  const int key2 = (lr >> 1) & 3;  // swizzle key for 64B-row buffers (sX*)

  __shared__ __align__(16) char sF[2 * 4096];
  __shared__ __align__(16) char sXw[2 * 8192];
  __shared__ __align__(16) char sXp[2 * 8192];

  // Xh B-operand fragments, loaded fp32 and packed in-register.
  bf16x8 xh[2][2];
#pragma unroll
  for (int bn = 0; bn < 2; ++bn)
#pragma unroll
    for (int s = 0; s < 2; ++s) {
      int b = m0 + wave * 32 + bn * 16 + lr;
      const float* xr = x + (size_t)b * 1024 + h * 64 + s * 32 + quad * 8;
      fl4 v0 = *(const fl4*)xr;
      fl4 v1 = *(const fl4*)(xr + 4);
      union { unsigned u[4]; bf16x8 v; } cv;
      cv.u[0] = pkbf(v0.x, v0.y);
      cv.u[1] = pkbf(v0.z, v0.w);
      cv.u[2] = pkbf(v1.x, v1.y);
      cv.u[3] = pkbf(v1.z, v1.w);
      xh[bn][s] = cv.v;
    }

  // ---- hoisted (loop-invariant) LDS byte offsets ----
  int af_off[2][2];  // B reads: sF row fm*16+lr, global chunk s*4+quad
#pragma unroll
  for (int fm = 0; fm < 2; ++fm)
#pragma unroll
    for (int s = 0; s < 2; ++s)
      af_off[fm][s] = (fm * 16 + lr) * 128 + (((s * 4 + quad) ^ key8) * 16);

  int cw_off[2][2];  // C writes: row wave*32+bn*16+lr, chunk fm*2+(quad>>1)
#pragma unroll
  for (int fm = 0; fm < 2; ++fm)
#pragma unroll
    for (int bn = 0; bn < 2; ++bn)
      cw_off[fm][bn] = (wave * 32 + bn * 16 + lr) * 64 +
                       (((fm * 2 + (quad >> 1)) ^ key2) * 16) + (quad & 1) * 8;

  int aw_off[8];  // D A reads: row fm*16+lr (all 128 b rows), chunk quad
#pragma unroll
  for (int fm = 0; fm < 8; ++fm)
    aw_off[fm] = (fm * 16 + lr) * 64 + ((quad ^ key2) * 16);

  // sF staging source (swizzle applied on the GLOBAL side)
  const char* srcF;
  {
    int row = t >> 3, c = t & 7, cs = c ^ (row & 7);
    srcF = (const char*)f_bf + h * 128 + (size_t)row * 2048 + cs * 16;
  }

  // Q addressing: block-uniform base (SGPR) + per-lane 32-bit byte offset.
  const char* qb1 = (const char*)Q1 + (size_t)(h * PP + n0) * FF * 2;
  const char* qb2 = (const char*)Q2 + (size_t)(h * PP + n0) * FF * 2;
  unsigned qo = (unsigned)(((wave * 64 + lr) * FF + quad * 8) * 2);

  f32x4 acc[8][4];
#pragma unroll
  for (int i2 = 0; i2 < 8; ++i2)
#pragma unroll
    for (int j = 0; j < 4; ++j) acc[i2][j] = (f32x4){0.f, 0.f, 0.f, 0.f};

  f32x4 xf[2][2];

// B(k): Xf from sF buf SFB into xf (8 MFMA)
#define BSTEP(SFB) do {                                                      \
    _Pragma("unroll") for (int fm_ = 0; fm_ < 2; ++fm_)                      \
      _Pragma("unroll") for (int bn_ = 0; bn_ < 2; ++bn_)                    \
        xf[fm_][bn_] = (f32x4){0.f, 0.f, 0.f, 0.f};                          \
    _Pragma("unroll") for (int s_ = 0; s_ < 2; ++s_)                         \
      _Pragma("unroll") for (int fm_ = 0; fm_ < 2; ++fm_) {                  \
        bf16x8 af_ = *(const bf16x8*)(sF + (SFB) + af_off[fm_][s_]);         \
        _Pragma("unroll") for (int bn_ = 0; bn_ < 2; ++bn_)                  \
          xf[fm_][bn_] = __builtin_amdgcn_mfma_f32_16x16x32_bf16(            \
              af_, xh[bn_][s_], xf[fm_][bn_], 0, 0, 0);                      \
      }                                                                      \
  } while (0)

// C pack group (FM,BN) -> sXw/sXp at byte base XB (~20 VALU + 2 ds_write)
#define CPACK(FM, BN, XB) do {                                               \
    float v0_ = xf[FM][BN][0], v1_ = xf[FM][BN][1];                          \
    float v2_ = xf[FM][BN][2], v3_ = xf[FM][BN][3];                          \
    float p0_ = fmaxf(v0_, 0.f), p1_ = fmaxf(v1_, 0.f);                      \
    float p2_ = fmaxf(v2_, 0.f), p3_ = fmaxf(v3_, 0.f);                      \
    u32x2 w_, p_;                                                            \
    w_.x = pkbf(v0_ * p0_, v1_ * p1_);                                       \
    w_.y = pkbf(v2_ * p2_, v3_ * p3_);                                       \
    p_.x = pkbf(p0_, p1_);                                                   \
    p_.y = pkbf(p2_, p3_);                                                   \
    *(u32x2*)(sXw + (XB) + cw_off[FM][BN]) = w_;                             \
    *(u32x2*)(sXp + (XB) + cw_off[FM][BN]) = p_;                             \
  } while (0)

// D operand reads for half HF from sX at byte base XA (8 ds_read_b128)
#define DREAD(HF, XA) do {                                                   \
    _Pragma("unroll") for (int fm_ = 0; fm_ < 4; ++fm_) {                    \
      aw[fm_] = *(const bf16x8*)(sXw + (XA) + aw_off[(HF) * 4 + fm_]);       \
      ap[fm_] = *(const bf16x8*)(sXp + (XA) + aw_off[(HF) * 4 + fm_]);       \
    }                                                                        \
  } while (0)

// D MFMA quarter: half HF, fn-pair FNP (16 MFMA)
#define DMFMA(HF, FNP) do {                                                  \
    _Pragma("unroll") for (int f2_ = 0; f2_ < 2; ++f2_) {                    \
      const int fn_ = (FNP) * 2 + f2_;                                       \
      _Pragma("unroll") for (int fm_ = 0; fm_ < 4; ++fm_) {                  \
        acc[(HF) * 4 + fm_][fn_] = __builtin_amdgcn_mfma_f32_16x16x32_bf16(  \
            aw[fm_], q1v[fn_], acc[(HF) * 4 + fm_][fn_], 0, 0, 0);           \
        acc[(HF) * 4 + fm_][fn_] = __builtin_amdgcn_mfma_f32_16x16x32_bf16(  \
            ap[fm_], q2v[fn_], acc[(HF) * 4 + fm_][fn_], 0, 0, 0);           \
      }                                                                      \
    }                                                                        \
  } while (0)

  // ---- prologue ----
  gload_lds16(srcF, sF + t * 16);
  srcF += 32 * 2048;
  asm volatile("s_waitcnt vmcnt(0)\n\ts_barrier" ::: "memory");
  __builtin_amdgcn_sched_barrier(0);
  gload_lds16(srcF, sF + 4096 + t * 16);
  srcF += 32 * 2048;
  BSTEP(0);
  CPACK(0, 0, 0);
  CPACK(0, 1, 0);
  CPACK(1, 0, 0);
  CPACK(1, 1, 0);
  asm volatile("s_waitcnt vmcnt(0) lgkmcnt(0)\n\ts_barrier" ::: "memory");
  __builtin_amdgcn_sched_barrier(0);

  for (int it = 0; it < FF / 32; ++it) {
    const int pA = it & 1;           // D reads sX[pA]; stage writes sF[pA]
    const int pB = pA ^ 1;           // B reads sF[pB]; C writes sX[pB]
    const int xa = pA * 8192, xb = pB * 8192;

    // Q fragment loads for D(it): uniform base + 32-bit voffset (L2 hits).
    bf16x8 q1v[4], q2v[4];
#pragma unroll
    for (int fn = 0; fn < 4; ++fn) {
      q1v[fn] = *(const bf16x8*)(qb1 + qo + fn * 131072);
      q2v[fn] = *(const bf16x8*)(qb2 + qo + fn * 131072);
    }
    qo += 64;

    // stage tile it+2 -> sF[pA] (newest vmem; drains at end barrier)
    gload_lds16(srcF, sF + pA * 4096 + t * 16);
    srcF += 32 * 2048;

    // B(it+1): 8 MFMAs; also cover D-hf0 ds_reads issued right after.
    BSTEP(pB * 4096);
    bf16x8 aw[4], ap[4];
    DREAD(0, xa);
    __builtin_amdgcn_sched_barrier(0);

    // interleaved chunks: {C group + 16 D MFMAs} x4, fenced so the
    // compiler cannot re-cluster VALU away from MFMA. DREAD(1) sits AFTER
    // DMFMA(0,1) (operand lifetime; round-5 bug fix) but in the SAME
    // region, so its ds_reads hoist under those MFMAs.
    __builtin_amdgcn_s_setprio(1);
    CPACK(0, 0, xb);
    DMFMA(0, 0);
    __builtin_amdgcn_sched_barrier(0);
    CPACK(0, 1, xb);
    DMFMA(0, 1);
    DREAD(1, xa);
    __builtin_amdgcn_sched_barrier(0);
    CPACK(1, 0, xb);
    DMFMA(1, 0);
    __builtin_amdgcn_sched_barrier(0);
    CPACK(1, 1, xb);
    DMFMA(1, 1);
    __builtin_amdgcn_s_setprio(0);

    // single per-body barrier: publishes C(it+1) sX writes, drains the sF
    // stage + Q loads, closes D(it) sX reads before next overwrite.
    asm volatile("s_waitcnt vmcnt(0) lgkmcnt(0)\n\ts_barrier" ::: "memory");
    __builtin_amdgcn_sched_barrier(0);
  }

  // epilogue: subtract pws, store fp32
#pragma unroll
  for (int fn = 0; fn < 4; ++fn) {
    int p = n0 + wave * 64 + fn * 16 + lr;
    float sub = pws[h * PP + p];
#pragma unroll
    for (int fm = 0; fm < 8; ++fm) {
      int brow = m0 + fm * 16 + quad * 4;
#pragma unroll
      for (int i2 = 0; i2 < 4; ++i2) {
        out[(size_t)(brow + i2) * (NH * PP) + h * PP + p] = acc[fm][fn][i2] - sub;
      }
    }
  }
}

extern "C" void kernel_launch(void* const* d_in, const int* in_sizes, int n_in,
                              void* d_out, int out_size, void* d_ws, size_t ws_size,
                              hipStream_t stream) {
  const float* x = (const float*)d_in[0];
  const float* features = (const float*)d_in[1];
  const float* prototypes = (const float*)d_in[2];
  const float* theta = (const float*)d_in[3];
  const float* alpha = (const float*)d_in[4];
  const float* beta = (const float*)d_in[5];
  float* out = (float*)d_out;

  char* ws = (char*)d_ws;
  size_t off = 0;
  auto carve = [&](size_t bytes) -> char* {
    char* p = ws + off;
    off += (bytes + 255) & ~(size_t)255;
    return p;
  };
  // f_bf padded by 64 rows: fused_main's pipelined loop prefetches up to two
  // tiles past the end (data unused; keeps the main loop branch-free).
  unsigned short* f_bf = (unsigned short*)carve((size_t)(FF + 64) * 1024 * 2);
  unsigned short* p_bf = (unsigned short*)carve((size_t)PP * 1024 * 2);
  unsigned short* Q1 = (unsigned short*)carve((size_t)NH * PP * FF * 2);
  unsigned short* Q2 = (unsigned short*)carve((size_t)NH * PP * FF * 2);
  float* pws = (float*)carve((size_t)NH * PP * 4);

  const int ncvt = (FF + PP) * 1024 / 4;
  cvt_fp<<<(ncvt + 255) / 256, 256, 0, stream>>>(features, prototypes, f_bf, p_bf);
  hipMemsetAsync(pws, 0, (size_t)NH * PP * 4, stream);

  // Phase 1: prototypes -> Q1, Q2, pws
  gemm_proto<<<dim3(FF / 128, PP / 128, NH), 256, 0, stream>>>(
      p_bf, f_bf, Q1, Q2, pws, theta, alpha, beta);

  // Fused main GEMM (1-D grid, XCD-aware decode in-kernel)
  fused_main<<<dim3(512, 1, 1), 256, 0, stream>>>(
      x, f_bf, Q1, Q2, pws, out);
}